// Round 1
// 591.072 us; speedup vs baseline: 1.0091x; 1.0091x over previous
//
#include <hip/hip_runtime.h>
#include <math.h>

// Problem constants (mirroring the reference)
#define IMG_H 480
#define IMG_W 640
#define DU    4
#define SUB_H 120          // IMG_H / DU
#define SUB_W 160          // IMG_W / DU
#define NPIX  (SUB_H * SUB_W)   // 19200
#define NSEM  16
#define NCH_IN 20          // 4 + NSEM input channels
#define VR    100
#define ZBINS 80           // MAX_VOX - MIN_VOX = 72 - (-8)
#define MIN_MAPPED 13      // 25/5 - (-8)
#define MAX_MAPPED 25      // int(89/5) - (-8)
#define NOUT  18           // 2 + NSEM
#define NCELL (VR * VR)    // 10000
#define NJOBS 16           // one job per sem channel; job0 also agent, job1 also explored
#define BLOCK 1024

// Grid = nframes * 16 = 256 blocks -> exactly 1 block/CU on MI355X (the old
// 17-job layout put 272 blocks on 256 CUs: 16 CUs ran 2 blocks and the whole
// dispatch waited ~2x a single block's time). Job k accumulates sem channel k
// into a 40KB LDS grid; job 0 additionally builds the agent-height grid
// (-> 3x3-dilated obstacle ch0) and job 1 the explored grid (ch1).
// MAP_T = EXP_T = 1.0 and occupancy counts are integers, so those two grids
// are binary after clip -- racy plain stores of 1.0f replace atomicAdd
// (bit-exact, no LDS atomic serialization). Only sem sums need ds_add.
__global__ __launch_bounds__(BLOCK, 1)
void ego_map_kernel(const float* __restrict__ obs,
                    float* __restrict__ out,
                    float f_pix) {
    __shared__ float acc[NCELL];        // sem grid for this job's channel
    __shared__ float acc2[NCELL];       // job0: agent grid; job1: explored grid

    const int f = blockIdx.x >> 4;      // / NJOBS
    const int j = blockIdx.x & 15;      // % NJOBS
    const int tid = threadIdx.x;

    for (int c = tid; c < NCELL; c += BLOCK) acc[c] = 0.0f;
    if (j < 2)
        for (int c = tid; c < NCELL; c += BLOCK) acc2[c] = 0.0f;
    __syncthreads();

    const float* frame    = obs + (size_t)f * NCH_IN * IMG_H * IMG_W;
    const float* depth_ch = frame + (size_t)3 * IMG_H * IMG_W;
    const float* sem_ch   = frame + (size_t)(4 + j) * IMG_H * IMG_W;

    for (int p = tid; p < NPIX; p += BLOCK) {
        int v = p / SUB_W;
        int u = p - v * SUB_W;
        size_t pix = (size_t)(v * DU) * IMG_W + (size_t)(u * DU);

        float depth = depth_ch[pix];
        if (!(depth > 20.0f && depth < 500.0f)) continue;

        // Match the np reference's fp32 op order exactly (true divisions --
        // no reciprocal rewrite, binning must be bit-exact).
        float uu = (float)(u * DU);
        float vv = (float)(v * DU);
        float X  = (uu - 320.0f) * depth / f_pix;
        float Zh = 88.0f + (240.0f - vv) * depth / f_pix;

        // np.round is half-to-even; rintf honors round-nearest-even.
        int xb = (int)rintf(X / 5.0f + 50.0f);
        int yb = (int)rintf(depth / 5.0f);
        int zb = (int)rintf(Zh / 5.0f) + 8;   // - MIN_VOX (= -8)

        if (xb < 0 || xb >= VR || yb < 0 || yb >= VR || zb < 0 || zb >= ZBINS)
            continue;

        int cell = yb * VR + xb;
        atomicAdd(&acc[cell], sem_ch[pix]);           // sem channel j sum
        if (j == 0) {
            if (zb >= MIN_MAPPED && zb < MAX_MAPPED)
                acc2[cell] = 1.0f;                    // agent grid (binary)
        } else if (j == 1) {
            acc2[cell] = 1.0f;                        // explored grid (binary)
        }
    }
    __syncthreads();

    float* outf = out + (size_t)f * NOUT * NCELL;

    // sem channel -> out ch 2+j
    {
        float* oc = outf + (size_t)(2 + j) * NCELL;
        for (int c = tid; c < NCELL; c += BLOCK)
            oc[c] = fminf(fmaxf(acc[c] / 5.0f, 0.0f), 1.0f);
    }

    if (j == 0) {
        // 3x3 max-dilate the (binary) agent grid from LDS, then clip.
        for (int c = tid; c < NCELL; c += BLOCK) {
            int y = c / VR;
            int x = c - y * VR;
            float m = 0.0f;
            int y0 = (y > 0) ? y - 1 : 0, y1 = (y < VR - 1) ? y + 1 : VR - 1;
            int x0 = (x > 0) ? x - 1 : 0, x1 = (x < VR - 1) ? x + 1 : VR - 1;
            for (int yy = y0; yy <= y1; ++yy)
                for (int xx = x0; xx <= x1; ++xx)
                    m = fmaxf(m, acc2[yy * VR + xx]);
            outf[c] = fminf(m, 1.0f);                              // obstacle
        }
    } else if (j == 1) {
        for (int c = tid; c < NCELL; c += BLOCK)
            outf[NCELL + c] = fminf(fmaxf(acc2[c], 0.0f), 1.0f);   // explored
    }
}

extern "C" void kernel_launch(void* const* d_in, const int* in_sizes, int n_in,
                              void* d_out, int out_size, void* d_ws, size_t ws_size,
                              hipStream_t stream) {
    const float* obs = (const float*)d_in[0];
    float* out = (float*)d_out;

    int nframes = in_sizes[0] / (NCH_IN * IMG_H * IMG_W);   // B*T = 16

    // F_PIX = W/2 / tan(deg2rad(HFOV/2)) in double like numpy, then fp32.
    float f_pix = (float)(IMG_W / 2.0 / tan((79.0 / 2.0) * M_PI / 180.0));

    ego_map_kernel<<<nframes * NJOBS, BLOCK, 0, stream>>>(obs, out, f_pix);
}